// Round 2
// baseline (532.809 us; speedup 1.0000x reference)
//
#include <hip/hip_runtime.h>

#define N_NODES 50000
#define N_EDGES 1600000
#define NCHUNK  ((N_NODES + 255) / 256)   // 196

typedef unsigned short ushort_t;
typedef __attribute__((ext_vector_type(8))) __bf16 bf16x8;
typedef __attribute__((ext_vector_type(4))) float  f32x4;

union FU { ushort_t s[8]; bf16x8 v; };

__device__ __forceinline__ ushort_t f2bf(float f) {
    union { float f; unsigned int i; } v; v.f = f;
    unsigned int r = v.i + 0x7fffu + ((v.i >> 16) & 1u);
    return (ushort_t)(r >> 16);
}
__device__ __forceinline__ float leaky(float x, float s) { return x >= 0.f ? x : s * x; }

// ---------------- K1: histogram of src ----------------
__global__ __launch_bounds__(256) void k_hist(const int* __restrict__ src, int* __restrict__ cnt) {
    int e = blockIdx.x * 256 + threadIdx.x;
    if (e < N_EDGES) atomicAdd(&cnt[src[e]], 1);
}

// ---------------- K2: exclusive scan of cnt -> cursor (+rowptr copy) ----------------
__global__ __launch_bounds__(256) void k_scan_chunk(const int* __restrict__ cnt, int* __restrict__ cursor,
                                                    int* __restrict__ blocksum) {
    __shared__ int buf[256];
    int t = threadIdx.x, i = blockIdx.x * 256 + t;
    int v = (i < N_NODES) ? cnt[i] : 0;
    buf[t] = v; __syncthreads();
    for (int off = 1; off < 256; off <<= 1) {
        int x = (t >= off) ? buf[t - off] : 0;
        __syncthreads(); buf[t] += x; __syncthreads();
    }
    int incl = buf[t];
    if (i < N_NODES) cursor[i] = incl - v;
    if (t == 255) blocksum[blockIdx.x] = incl;
}
__global__ __launch_bounds__(256) void k_scan_block(int* __restrict__ blocksum) {
    __shared__ int buf[256];
    int t = threadIdx.x;
    int v = (t < NCHUNK) ? blocksum[t] : 0;
    buf[t] = v; __syncthreads();
    for (int off = 1; off < 256; off <<= 1) {
        int x = (t >= off) ? buf[t - off] : 0;
        __syncthreads(); buf[t] += x; __syncthreads();
    }
    blocksum[t] = buf[t] - v;   // exclusive
}
__global__ __launch_bounds__(256) void k_scan_add(int* __restrict__ cursor, const int* __restrict__ blocksum,
                                                  int* __restrict__ rowptr) {
    int i = blockIdx.x * 256 + threadIdx.x;
    if (i < N_NODES) {
        int v = cursor[i] + blocksum[i >> 8];
        cursor[i] = v;
        rowptr[i] = v;     // persistent copy (cursor consumed by k_scatter)
    }
}

// ---------------- K3: CSR scatter of the edge PERMUTATION only (4 B/edge) ----------------
// Replaces the 64 B/edge fp16 msg-record scatter: payload drops 16x; the MLP moves into K4.
__global__ __launch_bounds__(256) void k_scatter(const int* __restrict__ src,
                                                 int* __restrict__ cursor, int* __restrict__ perm) {
    int e = blockIdx.x * 256 + threadIdx.x;
    if (e < N_EDGES) {
        int p = atomicAdd(&cursor[src[e]], 1);
        perm[p] = e;
    }
}

// ---------------- K4: fused edge-MLP + per-node moment reduce + feature build ----------------
// Wave per node, 4 nodes per wave (grid = 3125 blocks * 4 waves * 4 nodes = 50000).
// Per 16-edge tile: gather [x_t[tgt] | edge_attr] (ea rows are exactly one 64 B line ->
// efficient random reads, loaded nontemporally to keep x_t/tgt/perm L2-resident),
// run the 2-layer MLP via MFMA (same fragment layout as the proven k_mlp_scatter),
// accumulate masked power sums s1..s4 in registers. No msg materialization at all.
__global__ __launch_bounds__(256) void k_node_fused(
    const float* __restrict__ x_t, const float* __restrict__ ea,
    const float* __restrict__ w1a, const float* __restrict__ b1a,
    const float* __restrict__ w2a, const float* __restrict__ b2a,
    const int* __restrict__ tgt, const int* __restrict__ perm,
    const int* __restrict__ rowptr, const int* __restrict__ cnt,
    const float* __restrict__ x_s, const float* __restrict__ u,
    ushort_t* __restrict__ hcat, float* __restrict__ bnsum)
{
    if (blockIdx.x == 0 && threadIdx.x < 32) bnsum[threadIdx.x] = 0.f;
    __shared__ __align__(16) float    h_lds[4][16][36];   // wave-private h slice
    __shared__ __align__(4)  ushort_t stat_lds[4][128];   // wave-private stats staging
    const int t = threadIdx.x;
    const int w = t >> 6, L = t & 63, q = L >> 4, c = L & 15;

    // weight fragments (B-operand layout: col = c+16h, k = q*8+j) — identical to old k_mlp_scatter
    bf16x8 B1[2], B2[2];
    #pragma unroll
    for (int h = 0; h < 2; h++) {
        FU u1, u2;
        #pragma unroll
        for (int j = 0; j < 8; j++) {
            int kk = q * 8 + j, nn = c + 16 * h;
            u1.s[j] = f2bf(w1a[kk * 32 + nn]);
            u2.s[j] = f2bf(w2a[kk * 32 + nn]);
        }
        B1[h] = u1.v; B2[h] = u2.v;
    }
    const float bias1[2] = { b1a[c], b1a[c + 16] };
    const float bias2[2] = { b2a[c], b2a[c + 16] };
    const f32x4 zero = { 0.f, 0.f, 0.f, 0.f };

    const int nbase = (blockIdx.x * 4 + w) * 4;
    for (int kn = 0; kn < 4; kn++) {
        const int n = nbase + kn;
        const int start = rowptr[n], d = cnt[n];
        float s1a = 0.f, s2a = 0.f, s3a = 0.f, s4a = 0.f;   // feature c
        float s1b = 0.f, s2b = 0.f, s3b = 0.f, s4b = 0.f;   // feature c+16
        const int ntl = (d + 15) >> 4;

        for (int tl = 0; tl < ntl; tl++) {
            int row = tl * 16 + c;
            int ridx = row < d ? row : (d > 0 ? d - 1 : 0);  // clamp: dup rows masked below
            int e  = perm[start + ridx];
            int tg = tgt[e];
            const float* gp = (q < 2) ? (x_t + (size_t)tg * 16 + q * 8)
                                      : (ea + (size_t)e * 16 + (q - 2) * 8);
            f32x4 v0, v1;
            if (q < 2) { v0 = *(const f32x4*)gp; v1 = *((const f32x4*)gp + 1); }
            else       { v0 = __builtin_nontemporal_load((const f32x4*)gp);
                         v1 = __builtin_nontemporal_load((const f32x4*)gp + 1); }
            FU af;
            #pragma unroll
            for (int j = 0; j < 4; j++) { af.s[j] = f2bf(v0[j]); af.s[j + 4] = f2bf(v1[j]); }

            f32x4 a0 = __builtin_amdgcn_mfma_f32_16x16x32_bf16(af.v, B1[0], zero, 0, 0, 0);
            f32x4 a1 = __builtin_amdgcn_mfma_f32_16x16x32_bf16(af.v, B1[1], zero, 0, 0, 0);
            #pragma unroll
            for (int r = 0; r < 4; r++) {
                h_lds[w][q * 4 + r][c]      = leaky(a0[r] + bias1[0], 0.1f);
                h_lds[w][q * 4 + r][c + 16] = leaky(a1[r] + bias1[1], 0.1f);
            }
            __asm__ volatile("s_waitcnt lgkmcnt(0)" ::: "memory");

            float hv[8];
            __builtin_memcpy(&hv, &h_lds[w][c][q * 8], 32);
            FU hf;
            #pragma unroll
            for (int j = 0; j < 8; j++) hf.s[j] = f2bf(hv[j]);
            f32x4 m0 = __builtin_amdgcn_mfma_f32_16x16x32_bf16(hf.v, B2[0], zero, 0, 0, 0);
            f32x4 m1 = __builtin_amdgcn_mfma_f32_16x16x32_bf16(hf.v, B2[1], zero, 0, 0, 0);

            int rb = tl * 16 + q * 4;
            #pragma unroll
            for (int r = 0; r < 4; r++) {
                if (rb + r < d) {
                    float m = m0[r] + bias2[0], mm = m * m;
                    s1a += m;  s2a += mm; s3a += mm * m; s4a += mm * mm;
                    float x = m1[r] + bias2[1], xx = x * x;
                    s1b += x;  s2b += xx; s3b += xx * x; s4b += xx * xx;
                }
            }
            // next tile's h_lds writes are ordered after this tile's reads (per-wave in-order DS)
        }

        // reduce the 16-edge columns over q (lane = q*16+c -> xor 16, 32)
        s1a += __shfl_xor(s1a, 16); s1a += __shfl_xor(s1a, 32);
        s2a += __shfl_xor(s2a, 16); s2a += __shfl_xor(s2a, 32);
        s3a += __shfl_xor(s3a, 16); s3a += __shfl_xor(s3a, 32);
        s4a += __shfl_xor(s4a, 16); s4a += __shfl_xor(s4a, 32);
        s1b += __shfl_xor(s1b, 16); s1b += __shfl_xor(s1b, 32);
        s2b += __shfl_xor(s2b, 16); s2b += __shfl_xor(s2b, 32);
        s3b += __shfl_xor(s3b, 16); s3b += __shfl_xor(s3b, 32);
        s4b += __shfl_xor(s4b, 16); s4b += __shfl_xor(s4b, 32);

        if (q == 0) {
            float denom = fmaxf((float)d, 1.f);
            {   // feature c
                float mean = s1a / denom, m2r = s2a / denom, m3r = s3a / denom, m4r = s4a / denom;
                float var  = leaky(m2r - mean * mean, 0.01f);
                float stdv = sqrtf(var + 1e-6f);
                float e3   = m3r - 3.f * mean * m2r + 2.f * mean * mean * mean;
                float skew = e3 / (stdv * stdv * stdv);
                float e4   = m4r - 4.f * mean * m3r + 6.f * mean * mean * m2r
                             - 3.f * mean * mean * mean * mean;
                float kurt = e4 / (stdv * stdv * stdv * stdv);
                stat_lds[w][c]      = f2bf(mean);
                stat_lds[w][32 + c] = f2bf(stdv);
                stat_lds[w][64 + c] = f2bf(skew);
                stat_lds[w][96 + c] = f2bf(kurt);
            }
            {   // feature c+16
                float mean = s1b / denom, m2r = s2b / denom, m3r = s3b / denom, m4r = s4b / denom;
                float var  = leaky(m2r - mean * mean, 0.01f);
                float stdv = sqrtf(var + 1e-6f);
                float e3   = m3r - 3.f * mean * m2r + 2.f * mean * mean * mean;
                float skew = e3 / (stdv * stdv * stdv);
                float e4   = m4r - 4.f * mean * m3r + 6.f * mean * mean * m2r
                             - 3.f * mean * mean * mean * mean;
                float kurt = e4 / (stdv * stdv * stdv * stdv);
                stat_lds[w][16 + c]  = f2bf(mean);
                stat_lds[w][48 + c]  = f2bf(stdv);
                stat_lds[w][80 + c]  = f2bf(skew);
                stat_lds[w][112 + c] = f2bf(kurt);
            }
        }
        __asm__ volatile("s_waitcnt lgkmcnt(0)" ::: "memory");

        const size_t base = (size_t)n * 160;
        unsigned int sv;
        __builtin_memcpy(&sv, &stat_lds[w][L * 2], 4);
        *(unsigned int*)(hcat + base + 16 + L * 2) = sv;    // coalesced 256 B stats store
        if (L < 16) {
            hcat[base + L]       = f2bf(x_s[(size_t)n * 16 + L]);
            hcat[base + 144 + L] = f2bf(u[L]);
        }
    }
}

// ---------------- K5: GEMM1 [N,160]@[160,160] + bias + leaky -> h2 (bf16) ----------------
__global__ __launch_bounds__(256) void k_gemm1(const ushort_t* __restrict__ hcat,
                                               const float* __restrict__ w1b,
                                               const float* __restrict__ b1b,
                                               ushort_t* __restrict__ h2)
{
    __shared__ __align__(16) ushort_t W1T[160 * 168];
    int t = threadIdx.x;
    for (int i = t; i < 160 * 160; i += 256) { int k = i / 160, n = i % 160; W1T[n * 168 + k] = f2bf(w1b[i]); }
    __syncthreads();
    int w = t >> 6, L = t & 63, q = L >> 4, c = L & 15;
    const f32x4 zero = { 0.f, 0.f, 0.f, 0.f };
    for (int tile = blockIdx.x * 4 + w; tile < 3125 * 10; tile += gridDim.x * 4) {
        int rt = tile / 10, nt = tile % 10;
        int m = rt * 16 + c, n = nt * 16 + c;
        f32x4 acc = zero;
        #pragma unroll
        for (int ks = 0; ks < 5; ks++) {
            bf16x8 a; __builtin_memcpy(&a, hcat + (size_t)m * 160 + ks * 32 + q * 8, 16);
            bf16x8 b; __builtin_memcpy(&b, &W1T[n * 168 + ks * 32 + q * 8], 16);
            acc = __builtin_amdgcn_mfma_f32_16x16x32_bf16(a, b, acc, 0, 0, 0);
        }
        float bias = b1b[n];
        #pragma unroll
        for (int r = 0; r < 4; r++) {
            h2[(size_t)(rt * 16 + q * 4 + r) * 160 + n] = f2bf(leaky(acc[r] + bias, 0.1f));
        }
    }
}

// ---------------- K6: GEMM2 [N,160]@[160,16] + bias -> outpre (fp32) + BN partials ----------------
__global__ __launch_bounds__(256) void k_gemm2(const ushort_t* __restrict__ h2,
                                               const float* __restrict__ w2b,
                                               const float* __restrict__ b2b,
                                               float* __restrict__ outpre, float* __restrict__ bnsum)
{
    __shared__ __align__(16) ushort_t W2T[16 * 168];
    int t = threadIdx.x;
    for (int i = t; i < 160 * 16; i += 256) { int k = i / 16, n = i % 16; W2T[n * 168 + k] = f2bf(w2b[i]); }
    __syncthreads();
    int w = t >> 6, L = t & 63, q = L >> 4, c = L & 15;
    const f32x4 zero = { 0.f, 0.f, 0.f, 0.f };
    float ps = 0.f, ps2 = 0.f;
    float bias = b2b[c];
    for (int rt = blockIdx.x * 4 + w; rt < 3125; rt += gridDim.x * 4) {
        int m = rt * 16 + c;
        f32x4 acc = zero;
        #pragma unroll
        for (int ks = 0; ks < 5; ks++) {
            bf16x8 a; __builtin_memcpy(&a, h2 + (size_t)m * 160 + ks * 32 + q * 8, 16);
            bf16x8 b; __builtin_memcpy(&b, &W2T[c * 168 + ks * 32 + q * 8], 16);
            acc = __builtin_amdgcn_mfma_f32_16x16x32_bf16(a, b, acc, 0, 0, 0);
        }
        #pragma unroll
        for (int r = 0; r < 4; r++) {
            float v = acc[r] + bias;
            outpre[(size_t)(rt * 16 + q * 4 + r) * 16 + c] = v;
            ps += v; ps2 += v * v;
        }
    }
    ps  += __shfl_xor(ps, 16);  ps  += __shfl_xor(ps, 32);
    ps2 += __shfl_xor(ps2, 16); ps2 += __shfl_xor(ps2, 32);
    if (q == 0) {
        unsafeAtomicAdd(&bnsum[c], ps);
        unsafeAtomicAdd(&bnsum[16 + c], ps2);
    }
}

// ---------------- K7: BatchNorm apply -> d_out (fp32) ----------------
__global__ __launch_bounds__(256) void k_bn(const float* __restrict__ outpre, const float* __restrict__ bnsum,
                                            const float* __restrict__ gamma, const float* __restrict__ beta,
                                            float* __restrict__ out)
{
    int i = blockIdx.x * 256 + threadIdx.x;
    int c = i & 15;
    float x = outpre[i];
    float mu = bnsum[c] * (1.f / N_NODES);
    float var = bnsum[16 + c] * (1.f / N_NODES) - mu * mu;
    out[i] = gamma[c] * (x - mu) * rsqrtf(var + 1e-5f) + beta[c];
}

// ---------------- launch ----------------
extern "C" void kernel_launch(void* const* d_in, const int* in_sizes, int n_in,
                              void* d_out, int out_size, void* d_ws, size_t ws_size,
                              hipStream_t stream) {
    const float* x_s  = (const float*)d_in[0];
    const float* x_t  = (const float*)d_in[1];
    const float* ea   = (const float*)d_in[2];
    const float* u    = (const float*)d_in[3];
    const float* w1a  = (const float*)d_in[4];
    const float* b1a  = (const float*)d_in[5];
    const float* w2a  = (const float*)d_in[6];
    const float* b2a  = (const float*)d_in[7];
    const float* w1b  = (const float*)d_in[8];
    const float* b1b  = (const float*)d_in[9];
    const float* w2b  = (const float*)d_in[10];
    const float* b2b  = (const float*)d_in[11];
    const float* gam  = (const float*)d_in[12];
    const float* bet  = (const float*)d_in[13];
    const int* eidx   = (const int*)d_in[14];
    const int* src = eidx;
    const int* tgt = eidx + N_EDGES;

    char* ws = (char*)d_ws;
    // workspace layout (bytes) — ws_size >= 138,001,536 proven previously; max used here = 45.4 MB.
    //   cnt     [0        , 262,144)    int[50000], zeroed; live k_hist -> k_node_fused
    //   rowptr  [262,144  , 524,288)    int[50000]; live k_scan_add -> k_node_fused
    //   cursor  [524,288  , 786,432)    int[50000]; live scan -> k_scatter
    //   blksum  [786,432  , 787,456)    int[256]
    //   bnsum   [787,456  , 787,584)    float[32]  (zeroed by k_node_fused)
    //   outpre  [787,584  , 3,987,584)  float[800000]
    //   perm    [4,194,304, 10,594,304) int[1.6M]; live k_scatter -> k_node_fused
    //   hcat    [12,582,912, 28,582,912) bf16[50000*160]; live k_node_fused -> k_gemm1
    //   h2      [29,360,128, 45,360,128) bf16[50000*160]; live k_gemm1 -> k_gemm2
    const size_t OFF_CNT    = 0;
    const size_t OFF_ROWPTR = 262144;
    const size_t OFF_CURSOR = 524288;
    const size_t OFF_BLKSUM = 786432;
    const size_t OFF_BNSUM  = 787456;
    const size_t OFF_OUTPRE = 787584;
    const size_t OFF_PERM   = 4194304;
    const size_t OFF_HCAT   = 12582912;
    const size_t OFF_H2     = 29360128;

    int*   cnt     = (int*)(ws + OFF_CNT);
    int*   rowptr  = (int*)(ws + OFF_ROWPTR);
    int*   cursor  = (int*)(ws + OFF_CURSOR);
    int*   blksum  = (int*)(ws + OFF_BLKSUM);
    float* bnsum   = (float*)(ws + OFF_BNSUM);
    float* outpre  = (float*)(ws + OFF_OUTPRE);
    int*   perm    = (int*)(ws + OFF_PERM);
    ushort_t* hcat = (ushort_t*)(ws + OFF_HCAT);
    ushort_t* h2   = (ushort_t*)(ws + OFF_H2);

    (void)hipMemsetAsync(cnt, 0, 200000, stream);   // only cnt needs zeroing

    k_hist<<<(N_EDGES + 255) / 256, 256, 0, stream>>>(src, cnt);
    k_scan_chunk<<<NCHUNK, 256, 0, stream>>>(cnt, cursor, blksum);
    k_scan_block<<<1, 256, 0, stream>>>(blksum);
    k_scan_add<<<NCHUNK, 256, 0, stream>>>(cursor, blksum, rowptr);
    k_scatter<<<(N_EDGES + 255) / 256, 256, 0, stream>>>(src, cursor, perm);
    k_node_fused<<<N_NODES / 16, 256, 0, stream>>>(x_t, ea, w1a, b1a, w2a, b2a,
                                                   tgt, perm, rowptr, cnt, x_s, u, hcat, bnsum);
    k_gemm1<<<1024, 256, 0, stream>>>(hcat, w1b, b1b, h2);
    k_gemm2<<<512, 256, 0, stream>>>(h2, w2b, b2b, outpre, bnsum);
    k_bn<<<(N_NODES * 16) / 256, 256, 0, stream>>>(outpre, bnsum, gam, bet, (float*)d_out);
}

// Round 3
// 429.758 us; speedup vs baseline: 1.2398x; 1.2398x over previous
//
#include <hip/hip_runtime.h>

#define N_NODES 50000
#define N_EDGES 1600000

// counting-sort geometry
#define EPB 8192                         // edges per pass-1/2 block
#define NB1 ((N_EDGES + EPB - 1) / EPB)  // 196 edge-chunks
#define NPB 256                          // nodes per bucket (= blockDim for k_csr scan)
#define NBK ((N_NODES + NPB - 1) / NPB)  // 196 buckets
#define TBL (NBK * NB1)                  // 38416 table entries

typedef unsigned short ushort_t;
typedef __attribute__((ext_vector_type(8))) __bf16 bf16x8;
typedef __attribute__((ext_vector_type(4))) float  f32x4;

union FU { ushort_t s[8]; bf16x8 v; };

__device__ __forceinline__ ushort_t f2bf(float f) {
    union { float f; unsigned int i; } v; v.f = f;
    unsigned int r = v.i + 0x7fffu + ((v.i >> 16) & 1u);
    return (ushort_t)(r >> 16);
}
__device__ __forceinline__ float leaky(float x, float s) { return x >= 0.f ? x : s * x; }

// ---------------- K1: per-(bucket, edge-chunk) histogram ----------------
// LDS counters only; one coalesced table write per block. No global atomics.
__global__ __launch_bounds__(256) void k_bcount(const int* __restrict__ src, int* __restrict__ table) {
    __shared__ int cnt[NBK];
    const int t = threadIdx.x, blk = blockIdx.x;
    for (int i = t; i < NBK; i += 256) cnt[i] = 0;
    __syncthreads();
    const int base = blk * EPB;
    for (int i = t; i < EPB; i += 256) {
        int e = base + i;
        if (e < N_EDGES) atomicAdd(&cnt[src[e] >> 8], 1);   // NPB = 256 = 1<<8
    }
    __syncthreads();
    for (int b = t; b < NBK; b += 256) table[b * NB1 + blk] = cnt[b];
}

// ---------------- K2: exclusive scan of the flattened [bucket][chunk] table ----------------
// Single block; 256 threads each own a contiguous segment, carry via block scan.
__global__ __launch_bounds__(256) void k_bscan(int* __restrict__ table) {
    __shared__ int sums[256];
    const int t = threadIdx.x;
    const int SEG = (TBL + 255) / 256;                      // 151
    const int s0 = t * SEG, s1 = (s0 + SEG < TBL) ? s0 + SEG : TBL;
    int sum = 0;
    for (int i = s0; i < s1; i++) sum += table[i];
    sums[t] = sum; __syncthreads();
    for (int off = 1; off < 256; off <<= 1) {
        int x = (t >= off) ? sums[t - off] : 0;
        __syncthreads(); sums[t] += x; __syncthreads();
    }
    int carry = sums[t] - sum;                              // exclusive prefix of my segment
    for (int i = s0; i < s1; i++) { int v = table[i]; table[i] = carry; carry += v; }
}

// ---------------- K3: bucket-major scatter of (e, src) records ----------------
// LDS cursor atomics (no global atomics); each (bucket,chunk) run is a private
// contiguous region averaging 42 records = 336 B -> coalesced full-line writes.
__global__ __launch_bounds__(256) void k_bscatter(const int* __restrict__ src,
                                                  const int* __restrict__ table,
                                                  int2* __restrict__ ebuf) {
    __shared__ int cur[NBK];
    const int t = threadIdx.x, blk = blockIdx.x;
    for (int b = t; b < NBK; b += 256) cur[b] = table[b * NB1 + blk];
    __syncthreads();
    const int base = blk * EPB;
    for (int i = t; i < EPB; i += 256) {
        int e = base + i;
        if (e < N_EDGES) {
            int s = src[e];
            int pos = atomicAdd(&cur[s >> 8], 1);           // LDS atomic
            ebuf[pos] = make_int2(e, s);
        }
    }
}

// ---------------- K4: per-bucket CSR finalize ----------------
// One block per bucket. Bucket's records AND its perm region are contiguous and
// single-XCD: LDS count+scan -> rowptr/cnt (replaces hist+scan kernels), then
// in-bucket scatter whose 4 B stores merge in this XCD's L2 (full-line write-back).
__global__ __launch_bounds__(256) void k_csr(const int2* __restrict__ ebuf,
                                             const int* __restrict__ table,
                                             int* __restrict__ rowptr, int* __restrict__ cnt_g,
                                             int* __restrict__ perm) {
    __shared__ int cnt[NPB];
    __shared__ int scan[NPB];
    __shared__ int cur[NPB];
    const int t = threadIdx.x, b = blockIdx.x;
    const int base = table[b * NB1];
    const int end  = (b < NBK - 1) ? table[(b + 1) * NB1] : N_EDGES;
    cnt[t] = 0;
    __syncthreads();
    for (int i = base + t; i < end; i += 256) atomicAdd(&cnt[ebuf[i].y & (NPB - 1)], 1);
    __syncthreads();
    int v = cnt[t]; scan[t] = v; __syncthreads();
    for (int off = 1; off < 256; off <<= 1) {
        int x = (t >= off) ? scan[t - off] : 0;
        __syncthreads(); scan[t] += x; __syncthreads();
    }
    const int excl = scan[t] - v;
    const int n = b * NPB + t;
    if (n < N_NODES) { rowptr[n] = base + excl; cnt_g[n] = v; }
    cur[t] = base + excl;
    __syncthreads();
    for (int i = base + t; i < end; i += 256) {
        int2 es = ebuf[i];
        int pos = atomicAdd(&cur[es.y & (NPB - 1)], 1);     // LDS atomic
        perm[pos] = es.x;
    }
}

// ---------------- K5: fused edge-MLP + per-node moment reduce + feature build ----------------
// (unchanged from previous round — proven correct)
__global__ __launch_bounds__(256) void k_node_fused(
    const float* __restrict__ x_t, const float* __restrict__ ea,
    const float* __restrict__ w1a, const float* __restrict__ b1a,
    const float* __restrict__ w2a, const float* __restrict__ b2a,
    const int* __restrict__ tgt, const int* __restrict__ perm,
    const int* __restrict__ rowptr, const int* __restrict__ cnt,
    const float* __restrict__ x_s, const float* __restrict__ u,
    ushort_t* __restrict__ hcat, float* __restrict__ bnsum)
{
    if (blockIdx.x == 0 && threadIdx.x < 32) bnsum[threadIdx.x] = 0.f;
    __shared__ __align__(16) float    h_lds[4][16][36];   // wave-private h slice
    __shared__ __align__(4)  ushort_t stat_lds[4][128];   // wave-private stats staging
    const int t = threadIdx.x;
    const int w = t >> 6, L = t & 63, q = L >> 4, c = L & 15;

    bf16x8 B1[2], B2[2];
    #pragma unroll
    for (int h = 0; h < 2; h++) {
        FU u1, u2;
        #pragma unroll
        for (int j = 0; j < 8; j++) {
            int kk = q * 8 + j, nn = c + 16 * h;
            u1.s[j] = f2bf(w1a[kk * 32 + nn]);
            u2.s[j] = f2bf(w2a[kk * 32 + nn]);
        }
        B1[h] = u1.v; B2[h] = u2.v;
    }
    const float bias1[2] = { b1a[c], b1a[c + 16] };
    const float bias2[2] = { b2a[c], b2a[c + 16] };
    const f32x4 zero = { 0.f, 0.f, 0.f, 0.f };

    const int nbase = (blockIdx.x * 4 + w) * 4;
    for (int kn = 0; kn < 4; kn++) {
        const int n = nbase + kn;
        const int start = rowptr[n], d = cnt[n];
        float s1a = 0.f, s2a = 0.f, s3a = 0.f, s4a = 0.f;   // feature c
        float s1b = 0.f, s2b = 0.f, s3b = 0.f, s4b = 0.f;   // feature c+16
        const int ntl = (d + 15) >> 4;

        for (int tl = 0; tl < ntl; tl++) {
            int row = tl * 16 + c;
            int ridx = row < d ? row : (d > 0 ? d - 1 : 0);  // clamp: dup rows masked below
            int e  = perm[start + ridx];
            int tg = tgt[e];
            const float* gp = (q < 2) ? (x_t + (size_t)tg * 16 + q * 8)
                                      : (ea + (size_t)e * 16 + (q - 2) * 8);
            f32x4 v0, v1;
            if (q < 2) { v0 = *(const f32x4*)gp; v1 = *((const f32x4*)gp + 1); }
            else       { v0 = __builtin_nontemporal_load((const f32x4*)gp);
                         v1 = __builtin_nontemporal_load((const f32x4*)gp + 1); }
            FU af;
            #pragma unroll
            for (int j = 0; j < 4; j++) { af.s[j] = f2bf(v0[j]); af.s[j + 4] = f2bf(v1[j]); }

            f32x4 a0 = __builtin_amdgcn_mfma_f32_16x16x32_bf16(af.v, B1[0], zero, 0, 0, 0);
            f32x4 a1 = __builtin_amdgcn_mfma_f32_16x16x32_bf16(af.v, B1[1], zero, 0, 0, 0);
            #pragma unroll
            for (int r = 0; r < 4; r++) {
                h_lds[w][q * 4 + r][c]      = leaky(a0[r] + bias1[0], 0.1f);
                h_lds[w][q * 4 + r][c + 16] = leaky(a1[r] + bias1[1], 0.1f);
            }
            __asm__ volatile("s_waitcnt lgkmcnt(0)" ::: "memory");

            float hv[8];
            __builtin_memcpy(&hv, &h_lds[w][c][q * 8], 32);
            FU hf;
            #pragma unroll
            for (int j = 0; j < 8; j++) hf.s[j] = f2bf(hv[j]);
            f32x4 m0 = __builtin_amdgcn_mfma_f32_16x16x32_bf16(hf.v, B2[0], zero, 0, 0, 0);
            f32x4 m1 = __builtin_amdgcn_mfma_f32_16x16x32_bf16(hf.v, B2[1], zero, 0, 0, 0);

            int rb = tl * 16 + q * 4;
            #pragma unroll
            for (int r = 0; r < 4; r++) {
                if (rb + r < d) {
                    float m = m0[r] + bias2[0], mm = m * m;
                    s1a += m;  s2a += mm; s3a += mm * m; s4a += mm * mm;
                    float x = m1[r] + bias2[1], xx = x * x;
                    s1b += x;  s2b += xx; s3b += xx * x; s4b += xx * xx;
                }
            }
        }

        s1a += __shfl_xor(s1a, 16); s1a += __shfl_xor(s1a, 32);
        s2a += __shfl_xor(s2a, 16); s2a += __shfl_xor(s2a, 32);
        s3a += __shfl_xor(s3a, 16); s3a += __shfl_xor(s3a, 32);
        s4a += __shfl_xor(s4a, 16); s4a += __shfl_xor(s4a, 32);
        s1b += __shfl_xor(s1b, 16); s1b += __shfl_xor(s1b, 32);
        s2b += __shfl_xor(s2b, 16); s2b += __shfl_xor(s2b, 32);
        s3b += __shfl_xor(s3b, 16); s3b += __shfl_xor(s3b, 32);
        s4b += __shfl_xor(s4b, 16); s4b += __shfl_xor(s4b, 32);

        if (q == 0) {
            float denom = fmaxf((float)d, 1.f);
            {   // feature c
                float mean = s1a / denom, m2r = s2a / denom, m3r = s3a / denom, m4r = s4a / denom;
                float var  = leaky(m2r - mean * mean, 0.01f);
                float stdv = sqrtf(var + 1e-6f);
                float e3   = m3r - 3.f * mean * m2r + 2.f * mean * mean * mean;
                float skew = e3 / (stdv * stdv * stdv);
                float e4   = m4r - 4.f * mean * m3r + 6.f * mean * mean * m2r
                             - 3.f * mean * mean * mean * mean;
                float kurt = e4 / (stdv * stdv * stdv * stdv);
                stat_lds[w][c]      = f2bf(mean);
                stat_lds[w][32 + c] = f2bf(stdv);
                stat_lds[w][64 + c] = f2bf(skew);
                stat_lds[w][96 + c] = f2bf(kurt);
            }
            {   // feature c+16
                float mean = s1b / denom, m2r = s2b / denom, m3r = s3b / denom, m4r = s4b / denom;
                float var  = leaky(m2r - mean * mean, 0.01f);
                float stdv = sqrtf(var + 1e-6f);
                float e3   = m3r - 3.f * mean * m2r + 2.f * mean * mean * mean;
                float skew = e3 / (stdv * stdv * stdv);
                float e4   = m4r - 4.f * mean * m3r + 6.f * mean * mean * m2r
                             - 3.f * mean * mean * mean * mean;
                float kurt = e4 / (stdv * stdv * stdv * stdv);
                stat_lds[w][16 + c]  = f2bf(mean);
                stat_lds[w][48 + c]  = f2bf(stdv);
                stat_lds[w][80 + c]  = f2bf(skew);
                stat_lds[w][112 + c] = f2bf(kurt);
            }
        }
        __asm__ volatile("s_waitcnt lgkmcnt(0)" ::: "memory");

        const size_t base = (size_t)n * 160;
        unsigned int sv;
        __builtin_memcpy(&sv, &stat_lds[w][L * 2], 4);
        *(unsigned int*)(hcat + base + 16 + L * 2) = sv;    // coalesced 256 B stats store
        if (L < 16) {
            hcat[base + L]       = f2bf(x_s[(size_t)n * 16 + L]);
            hcat[base + 144 + L] = f2bf(u[L]);
        }
    }
}

// ---------------- K6: GEMM1 [N,160]@[160,160] + bias + leaky -> h2 (bf16) ----------------
__global__ __launch_bounds__(256) void k_gemm1(const ushort_t* __restrict__ hcat,
                                               const float* __restrict__ w1b,
                                               const float* __restrict__ b1b,
                                               ushort_t* __restrict__ h2)
{
    __shared__ __align__(16) ushort_t W1T[160 * 168];
    int t = threadIdx.x;
    for (int i = t; i < 160 * 160; i += 256) { int k = i / 160, n = i % 160; W1T[n * 168 + k] = f2bf(w1b[i]); }
    __syncthreads();
    int w = t >> 6, L = t & 63, q = L >> 4, c = L & 15;
    const f32x4 zero = { 0.f, 0.f, 0.f, 0.f };
    for (int tile = blockIdx.x * 4 + w; tile < 3125 * 10; tile += gridDim.x * 4) {
        int rt = tile / 10, nt = tile % 10;
        int m = rt * 16 + c, n = nt * 16 + c;
        f32x4 acc = zero;
        #pragma unroll
        for (int ks = 0; ks < 5; ks++) {
            bf16x8 a; __builtin_memcpy(&a, hcat + (size_t)m * 160 + ks * 32 + q * 8, 16);
            bf16x8 b; __builtin_memcpy(&b, &W1T[n * 168 + ks * 32 + q * 8], 16);
            acc = __builtin_amdgcn_mfma_f32_16x16x32_bf16(a, b, acc, 0, 0, 0);
        }
        float bias = b1b[n];
        #pragma unroll
        for (int r = 0; r < 4; r++) {
            h2[(size_t)(rt * 16 + q * 4 + r) * 160 + n] = f2bf(leaky(acc[r] + bias, 0.1f));
        }
    }
}

// ---------------- K7: GEMM2 [N,160]@[160,16] + bias -> outpre (fp32) + BN partials ----------------
__global__ __launch_bounds__(256) void k_gemm2(const ushort_t* __restrict__ h2,
                                               const float* __restrict__ w2b,
                                               const float* __restrict__ b2b,
                                               float* __restrict__ outpre, float* __restrict__ bnsum)
{
    __shared__ __align__(16) ushort_t W2T[16 * 168];
    int t = threadIdx.x;
    for (int i = t; i < 160 * 16; i += 256) { int k = i / 16, n = i % 16; W2T[n * 168 + k] = f2bf(w2b[i]); }
    __syncthreads();
    int w = t >> 6, L = t & 63, q = L >> 4, c = L & 15;
    const f32x4 zero = { 0.f, 0.f, 0.f, 0.f };
    float ps = 0.f, ps2 = 0.f;
    float bias = b2b[c];
    for (int rt = blockIdx.x * 4 + w; rt < 3125; rt += gridDim.x * 4) {
        int m = rt * 16 + c;
        f32x4 acc = zero;
        #pragma unroll
        for (int ks = 0; ks < 5; ks++) {
            bf16x8 a; __builtin_memcpy(&a, h2 + (size_t)m * 160 + ks * 32 + q * 8, 16);
            bf16x8 b; __builtin_memcpy(&b, &W2T[c * 168 + ks * 32 + q * 8], 16);
            acc = __builtin_amdgcn_mfma_f32_16x16x32_bf16(a, b, acc, 0, 0, 0);
        }
        #pragma unroll
        for (int r = 0; r < 4; r++) {
            float v = acc[r] + bias;
            outpre[(size_t)(rt * 16 + q * 4 + r) * 16 + c] = v;
            ps += v; ps2 += v * v;
        }
    }
    ps  += __shfl_xor(ps, 16);  ps  += __shfl_xor(ps, 32);
    ps2 += __shfl_xor(ps2, 16); ps2 += __shfl_xor(ps2, 32);
    if (q == 0) {
        unsafeAtomicAdd(&bnsum[c], ps);
        unsafeAtomicAdd(&bnsum[16 + c], ps2);
    }
}

// ---------------- K8: BatchNorm apply -> d_out (fp32) ----------------
__global__ __launch_bounds__(256) void k_bn(const float* __restrict__ outpre, const float* __restrict__ bnsum,
                                            const float* __restrict__ gamma, const float* __restrict__ beta,
                                            float* __restrict__ out)
{
    int i = blockIdx.x * 256 + threadIdx.x;
    int c = i & 15;
    float x = outpre[i];
    float mu = bnsum[c] * (1.f / N_NODES);
    float var = bnsum[16 + c] * (1.f / N_NODES) - mu * mu;
    out[i] = gamma[c] * (x - mu) * rsqrtf(var + 1e-5f) + beta[c];
}

// ---------------- launch ----------------
extern "C" void kernel_launch(void* const* d_in, const int* in_sizes, int n_in,
                              void* d_out, int out_size, void* d_ws, size_t ws_size,
                              hipStream_t stream) {
    const float* x_s  = (const float*)d_in[0];
    const float* x_t  = (const float*)d_in[1];
    const float* ea   = (const float*)d_in[2];
    const float* u    = (const float*)d_in[3];
    const float* w1a  = (const float*)d_in[4];
    const float* b1a  = (const float*)d_in[5];
    const float* w2a  = (const float*)d_in[6];
    const float* b2a  = (const float*)d_in[7];
    const float* w1b  = (const float*)d_in[8];
    const float* b1b  = (const float*)d_in[9];
    const float* w2b  = (const float*)d_in[10];
    const float* b2b  = (const float*)d_in[11];
    const float* gam  = (const float*)d_in[12];
    const float* bet  = (const float*)d_in[13];
    const int* eidx   = (const int*)d_in[14];
    const int* src = eidx;
    const int* tgt = eidx + N_EDGES;

    char* ws = (char*)d_ws;
    // workspace layout (bytes) — ws_size >= 138,001,536 proven; max used here = 58.9 MB.
    //   cnt_g   [0        , 262,144)    int[50000]; written by k_csr -> read k_node_fused
    //   rowptr  [262,144  , 524,288)    int[50000]; written by k_csr -> read k_node_fused
    //   table   [524,288  , 786,432)    int[38416]; k_bcount -> k_bscan -> k_bscatter/k_csr
    //   bnsum   [787,456  , 787,584)    float[32]  (zeroed by k_node_fused blk 0)
    //   outpre  [787,584  , 3,987,584)  float[800000]
    //   perm    [4,194,304, 10,594,304) int[1.6M]; k_csr -> k_node_fused
    //   hcat    [12,582,912, 28,582,912) bf16[50000*160]; k_node_fused -> k_gemm1
    //   h2      [29,360,128, 45,360,128) bf16[50000*160]; k_gemm1 -> k_gemm2
    //   ebuf    [46,137,344, 58,937,344) int2[1.6M]; k_bscatter -> k_csr
    const size_t OFF_CNT    = 0;
    const size_t OFF_ROWPTR = 262144;
    const size_t OFF_TABLE  = 524288;
    const size_t OFF_BNSUM  = 787456;
    const size_t OFF_OUTPRE = 787584;
    const size_t OFF_PERM   = 4194304;
    const size_t OFF_HCAT   = 12582912;
    const size_t OFF_H2     = 29360128;
    const size_t OFF_EBUF   = 46137344;

    int*   cnt_g   = (int*)(ws + OFF_CNT);
    int*   rowptr  = (int*)(ws + OFF_ROWPTR);
    int*   table   = (int*)(ws + OFF_TABLE);
    float* bnsum   = (float*)(ws + OFF_BNSUM);
    float* outpre  = (float*)(ws + OFF_OUTPRE);
    int*   perm    = (int*)(ws + OFF_PERM);
    ushort_t* hcat = (ushort_t*)(ws + OFF_HCAT);
    ushort_t* h2   = (ushort_t*)(ws + OFF_H2);
    int2*  ebuf    = (int2*)(ws + OFF_EBUF);

    // no memsets needed: table/cnt/rowptr fully overwritten; bnsum zeroed on-device

    k_bcount  <<<NB1, 256, 0, stream>>>(src, table);
    k_bscan   <<<1,   256, 0, stream>>>(table);
    k_bscatter<<<NB1, 256, 0, stream>>>(src, table, ebuf);
    k_csr     <<<NBK, 256, 0, stream>>>(ebuf, table, rowptr, cnt_g, perm);
    k_node_fused<<<N_NODES / 16, 256, 0, stream>>>(x_t, ea, w1a, b1a, w2a, b2a,
                                                   tgt, perm, rowptr, cnt_g, x_s, u, hcat, bnsum);
    k_gemm1<<<1024, 256, 0, stream>>>(hcat, w1b, b1b, h2);
    k_gemm2<<<512, 256, 0, stream>>>(h2, w2b, b2b, outpre, bnsum);
    k_bn<<<(N_NODES * 16) / 256, 256, 0, stream>>>(outpre, bnsum, gam, bet, (float*)d_out);
}